// Round 3
// baseline (832.857 us; speedup 1.0000x reference)
//
#include <hip/hip_runtime.h>

#define N_HID 128
#define BM 64
#define BK 32
#define LDA 36   // BK + 4 pad (words) — keeps 16B alignment, breaks bank aliasing

// ---------------------------------------------------------------------------
// Fused dual GEMM via LDS tiles: msg = h @ We^T ; out = h @ Ws^T + b
// 256 thr, BM=64 rows/block, BK=32 k-chunk. All global loads coalesced float4;
// LDS reads are b128 with <=2-way bank aliasing (free). Thread tile:
// rows rg*4+i (rg=t>>4), cols cg+16*j (cg=t&15) in BOTH We and Ws outputs.
// ---------------------------------------------------------------------------
__global__ __launch_bounds__(256) void gemm_dual(
    const float* __restrict__ h,
    const float* __restrict__ We,
    const float* __restrict__ Ws,
    const float* __restrict__ bs,
    float* __restrict__ msg,
    float* __restrict__ outSelf,
    int n)
{
    __shared__ float As[BM * LDA];        //  9 KB
    __shared__ float Es[N_HID * LDA];     // 18 KB
    __shared__ float Ss[N_HID * LDA];     // 18 KB

    const int t    = threadIdx.x;
    const int cg   = t & 15;
    const int rg   = t >> 4;
    const int row0 = blockIdx.x * BM;

    float accE[4][8], accS[4][8];
#pragma unroll
    for (int i = 0; i < 4; ++i)
#pragma unroll
        for (int j = 0; j < 8; ++j) { accE[i][j] = 0.f; accS[i][j] = 0.f; }

    for (int k0 = 0; k0 < N_HID; k0 += BK) {
        __syncthreads();   // protect LDS from previous iter's readers
        // ---- stage A: 64 rows x 32 k = 512 float4, 2 per thread ----
#pragma unroll
        for (int p = 0; p < 2; ++p) {
            int f  = t + p * 256;
            int r  = f >> 3, ks = f & 7;
            int gr = row0 + r; if (gr > n - 1) gr = n - 1;
            float4 v = *(const float4*)&h[(size_t)gr * N_HID + k0 + ks * 4];
            *(float4*)&As[r * LDA + ks * 4] = v;
        }
        // ---- stage We/Ws: 128 cols x 32 k = 1024 float4 each, 4/thread ----
#pragma unroll
        for (int p = 0; p < 4; ++p) {
            int f = t + p * 256;
            int c = f >> 3, ks = f & 7;
            float4 ve = *(const float4*)&We[c * N_HID + k0 + ks * 4];
            float4 vs = *(const float4*)&Ws[c * N_HID + k0 + ks * 4];
            *(float4*)&Es[c * LDA + ks * 4] = ve;
            *(float4*)&Ss[c * LDA + ks * 4] = vs;
        }
        __syncthreads();

        // ---- compute: 8 k-steps of 4 ----
#pragma unroll
        for (int ks = 0; ks < BK; ks += 4) {
            float4 a[4];
#pragma unroll
            for (int i = 0; i < 4; ++i)
                a[i] = *(const float4*)&As[(rg * 4 + i) * LDA + ks];
#pragma unroll
            for (int j = 0; j < 8; ++j) {
                float4 we = *(const float4*)&Es[(cg + 16 * j) * LDA + ks];
#pragma unroll
                for (int i = 0; i < 4; ++i)
                    accE[i][j] += a[i].x * we.x + a[i].y * we.y
                                + a[i].z * we.z + a[i].w * we.w;
                float4 ws = *(const float4*)&Ss[(cg + 16 * j) * LDA + ks];
#pragma unroll
                for (int i = 0; i < 4; ++i)
                    accS[i][j] += a[i].x * ws.x + a[i].y * ws.y
                                + a[i].z * ws.z + a[i].w * ws.w;
            }
        }
    }

    float bb[8];
#pragma unroll
    for (int j = 0; j < 8; ++j) bb[j] = bs[cg + 16 * j];

#pragma unroll
    for (int i = 0; i < 4; ++i) {
        int row = row0 + rg * 4 + i;
        if (row < n) {
#pragma unroll
            for (int j = 0; j < 8; ++j) {
                msg[(size_t)row * N_HID + cg + 16 * j]     = accE[i][j];
                outSelf[(size_t)row * N_HID + cg + 16 * j] = accS[i][j] + bb[j];
            }
        }
    }
}

// ---------------------------------------------------------------------------
// Degree count: 800k int atomics over 50k counters (L2-resident).
// ---------------------------------------------------------------------------
__global__ void count_deg(const int* __restrict__ dst, int* __restrict__ deg, int E)
{
    int e = blockIdx.x * blockDim.x + threadIdx.x;
    if (e < E) atomicAdd(&deg[dst[e]], 1);
}

// ---------------------------------------------------------------------------
// Multi-block exclusive scan, 3 phases (replaces serial single-block scan).
// ---------------------------------------------------------------------------
__global__ __launch_bounds__(256) void scan_block(
    const int* __restrict__ deg, int* __restrict__ offs, int* __restrict__ bsum, int n)
{
    __shared__ int wsum[4];
    int t    = threadIdx.x;
    int lane = t & 63;
    int wid  = t >> 6;
    int idx  = blockIdx.x * 256 + t;
    int v    = (idx < n) ? deg[idx] : 0;
    int val  = v;
#pragma unroll
    for (int off = 1; off < 64; off <<= 1) {
        int y = __shfl_up(val, off);
        if (lane >= off) val += y;
    }
    if (lane == 63) wsum[wid] = val;
    __syncthreads();
    if (t == 0) {
        int s = 0;
#pragma unroll
        for (int w = 0; w < 4; ++w) { int tmp = wsum[w]; wsum[w] = s; s += tmp; }
    }
    __syncthreads();
    int excl = wsum[wid] + val - v;
    if (idx < n) offs[idx] = excl;
    if (t == 255) bsum[blockIdx.x] = wsum[3] + val;   // block total
}

__global__ __launch_bounds__(256) void scan_bsums(
    int* __restrict__ bsum, int* __restrict__ bexcl, int* __restrict__ offs, int nb, int n)
{
    __shared__ int wsum[4];
    int t    = threadIdx.x;
    int lane = t & 63;
    int wid  = t >> 6;
    int v    = (t < nb) ? bsum[t] : 0;
    int val  = v;
#pragma unroll
    for (int off = 1; off < 64; off <<= 1) {
        int y = __shfl_up(val, off);
        if (lane >= off) val += y;
    }
    if (lane == 63) wsum[wid] = val;
    __syncthreads();
    if (t == 0) {
        int s = 0;
#pragma unroll
        for (int w = 0; w < 4; ++w) { int tmp = wsum[w]; wsum[w] = s; s += tmp; }
    }
    __syncthreads();
    int excl = wsum[wid] + val - v;
    if (t < nb) bexcl[t] = excl;
    if (t == 255) offs[n] = wsum[3] + val;   // grand total = E
}

__global__ __launch_bounds__(256) void scan_apply(
    int* __restrict__ offs, int* __restrict__ cursor, const int* __restrict__ bexcl, int n)
{
    int idx = blockIdx.x * 256 + threadIdx.x;
    if (idx < n) {
        int o = offs[idx] + bexcl[blockIdx.x];
        offs[idx]   = o;
        cursor[idx] = o;
    }
}

// ---------------------------------------------------------------------------
// CSR fill: pos = cursor[dst]++ ; csr[pos] = src.
// ---------------------------------------------------------------------------
__global__ void scatter_edges(const int* __restrict__ src,
                              const int* __restrict__ dst,
                              int* __restrict__ cursor, int* __restrict__ csr, int E)
{
    int e = blockIdx.x * blockDim.x + threadIdx.x;
    if (e < E) {
        int d   = dst[e];
        int pos = atomicAdd(&cursor[d], 1);
        csr[pos] = src[e];
    }
}

// ---------------------------------------------------------------------------
// Per-node gather + mean + self + relu. One wave per node, float2 per lane.
// out already holds self part (h@Ws^T+b); update in place.
// ---------------------------------------------------------------------------
__global__ __launch_bounds__(256) void gather_finish(
    const int* __restrict__ offs,
    const int* __restrict__ csr,
    const float* __restrict__ msg,
    float* __restrict__ out,
    int n)
{
    int node = blockIdx.x * 4 + (threadIdx.x >> 6);
    if (node >= n) return;
    int lane  = threadIdx.x & 63;
    int start = offs[node];
    int end   = offs[node + 1];

    const float2* m2 = (const float2*)msg;
    float ax = 0.f, ay = 0.f;
    int i = start;
    for (; i + 4 <= end; i += 4) {
        int s0 = csr[i + 0], s1 = csr[i + 1], s2 = csr[i + 2], s3 = csr[i + 3];
        float2 v0 = m2[(size_t)s0 * 64 + lane];
        float2 v1 = m2[(size_t)s1 * 64 + lane];
        float2 v2 = m2[(size_t)s2 * 64 + lane];
        float2 v3 = m2[(size_t)s3 * 64 + lane];
        ax += v0.x + v1.x + v2.x + v3.x;
        ay += v0.y + v1.y + v2.y + v3.y;
    }
    for (; i < end; ++i) {
        int s = csr[i];
        float2 v = m2[(size_t)s * 64 + lane];
        ax += v.x; ay += v.y;
    }

    int   d  = end - start;
    float sc = d > 0 ? 1.0f / (float)d : 0.f;

    float2* o2 = (float2*)out;
    float2 sv  = o2[(size_t)node * 64 + lane];
    float2 r;
    r.x = fmaxf(sv.x + ax * sc, 0.f);
    r.y = fmaxf(sv.y + ay * sc, 0.f);
    o2[(size_t)node * 64 + lane] = r;
}

// ---------------------------------------------------------------------------
extern "C" void kernel_launch(void* const* d_in, const int* in_sizes, int n_in,
                              void* d_out, int out_size, void* d_ws, size_t ws_size,
                              hipStream_t stream)
{
    const float* h   = (const float*)d_in[0];
    const int*   src = (const int*)d_in[1];   // harness passes integer inputs as int32
    const int*   dst = (const int*)d_in[2];
    const float* We  = (const float*)d_in[3];
    const float* Ws  = (const float*)d_in[4];
    const float* bs  = (const float*)d_in[5];
    float*       out = (float*)d_out;

    const int n = in_sizes[0] / N_HID;   // 50000
    const int E = in_sizes[1];           // 800000

    // workspace layout (~29.5 MB)
    float* msg    = (float*)d_ws;                       // n*128 f32
    int*   deg    = (int*)(msg + (size_t)n * N_HID);    // n
    int*   offs   = deg + n;                            // n+1 (+pad)
    int*   cursor = offs + (n + 8);                     // n
    int*   csr    = cursor + n;                         // E
    int*   bsum   = csr + E;                            // 256
    int*   bexcl  = bsum + 256;                         // 256

    const int nbScan = (n + 255) / 256;                 // 196

    hipMemsetAsync(deg, 0, sizeof(int) * (size_t)n, stream);
    count_deg<<<(E + 255) / 256, 256, 0, stream>>>(dst, deg, E);
    scan_block<<<nbScan, 256, 0, stream>>>(deg, offs, bsum, n);
    scan_bsums<<<1, 256, 0, stream>>>(bsum, bexcl, offs, nbScan, n);
    scan_apply<<<nbScan, 256, 0, stream>>>(offs, cursor, bexcl, n);
    scatter_edges<<<(E + 255) / 256, 256, 0, stream>>>(src, dst, cursor, csr, E);
    gemm_dual<<<(n + BM - 1) / BM, 256, 0, stream>>>(h, We, Ws, bs, msg, out, n);
    gather_finish<<<(n + 3) / 4, 256, 0, stream>>>(offs, csr, msg, out, n);
}

// Round 4
// 377.515 us; speedup vs baseline: 2.2062x; 2.2062x over previous
//
#include <hip/hip_runtime.h>

#define N_HID 128
#define BM 64
#define BK 32
#define LDA 36   // BK + 4 pad (words) — keeps 16B alignment, breaks bank aliasing

// ---------------------------------------------------------------------------
// Dual GEMM via LDS tiles, TWO SEQUENTIAL PASSES to keep only 32 accumulators
// live (R3's fused version spilled: VGPR=256, 1.2GB scratch writes).
// pass 0: msg = h @ We^T ; pass 1: outSelf = h @ Ws^T + b.
// 256 thr, BM=64 rows/block, BK=32 k-chunk. Coalesced float4 global loads;
// b128 LDS reads with <=2-way bank aliasing (free on gfx950).
// ---------------------------------------------------------------------------
__global__ __launch_bounds__(256) void gemm_dual(
    const float* __restrict__ h,
    const float* __restrict__ We,
    const float* __restrict__ Ws,
    const float* __restrict__ bs,
    float* __restrict__ msg,
    float* __restrict__ outSelf,
    int n)
{
    __shared__ float As[BM * LDA];        //  9 KB
    __shared__ float Wsh[N_HID * LDA];    // 18 KB

    const int t    = threadIdx.x;
    const int cg   = t & 15;
    const int rg   = t >> 4;
    const int row0 = blockIdx.x * BM;

#pragma unroll 1
    for (int pass = 0; pass < 2; ++pass) {
        const float* Wm = (pass == 0) ? We : Ws;

        float acc[4][8];
#pragma unroll
        for (int i = 0; i < 4; ++i)
#pragma unroll
            for (int j = 0; j < 8; ++j) acc[i][j] = 0.f;

#pragma unroll 1
        for (int k0 = 0; k0 < N_HID; k0 += BK) {
            __syncthreads();   // protect LDS from previous iter's readers
            // ---- stage A: 64 rows x 32 k = 512 float4, 2 per thread ----
#pragma unroll
            for (int p = 0; p < 2; ++p) {
                int f  = t + p * 256;
                int r  = f >> 3, ks = f & 7;
                int gr = row0 + r; if (gr > n - 1) gr = n - 1;
                float4 v = *(const float4*)&h[(size_t)gr * N_HID + k0 + ks * 4];
                *(float4*)&As[r * LDA + ks * 4] = v;
            }
            // ---- stage W: 128 cols x 32 k = 1024 float4, 4 per thread ----
#pragma unroll
            for (int p = 0; p < 4; ++p) {
                int f = t + p * 256;
                int c = f >> 3, ks = f & 7;
                float4 v = *(const float4*)&Wm[c * N_HID + k0 + ks * 4];
                *(float4*)&Wsh[c * LDA + ks * 4] = v;
            }
            __syncthreads();

            // ---- compute: 8 k-steps of 4 ----
#pragma unroll
            for (int ks = 0; ks < BK; ks += 4) {
                float4 a[4];
#pragma unroll
                for (int i = 0; i < 4; ++i)
                    a[i] = *(const float4*)&As[(rg * 4 + i) * LDA + ks];
#pragma unroll
                for (int j = 0; j < 8; ++j) {
                    float4 w = *(const float4*)&Wsh[(cg + 16 * j) * LDA + ks];
#pragma unroll
                    for (int i = 0; i < 4; ++i)
                        acc[i][j] += a[i].x * w.x + a[i].y * w.y
                                   + a[i].z * w.z + a[i].w * w.w;
                }
            }
        }

        // ---- epilogue for this pass ----
        if (pass == 0) {
#pragma unroll
            for (int i = 0; i < 4; ++i) {
                int row = row0 + rg * 4 + i;
                if (row < n) {
#pragma unroll
                    for (int j = 0; j < 8; ++j)
                        msg[(size_t)row * N_HID + cg + 16 * j] = acc[i][j];
                }
            }
        } else {
            float bb[8];
#pragma unroll
            for (int j = 0; j < 8; ++j) bb[j] = bs[cg + 16 * j];
#pragma unroll
            for (int i = 0; i < 4; ++i) {
                int row = row0 + rg * 4 + i;
                if (row < n) {
#pragma unroll
                    for (int j = 0; j < 8; ++j)
                        outSelf[(size_t)row * N_HID + cg + 16 * j] = acc[i][j] + bb[j];
                }
            }
        }
    }
}

// ---------------------------------------------------------------------------
// Degree count: 800k int atomics over 50k counters (L2-resident).
// ---------------------------------------------------------------------------
__global__ void count_deg(const int* __restrict__ dst, int* __restrict__ deg, int E)
{
    int e = blockIdx.x * blockDim.x + threadIdx.x;
    if (e < E) atomicAdd(&deg[dst[e]], 1);
}

// ---------------------------------------------------------------------------
// Multi-block exclusive scan, 3 phases.
// ---------------------------------------------------------------------------
__global__ __launch_bounds__(256) void scan_block(
    const int* __restrict__ deg, int* __restrict__ offs, int* __restrict__ bsum, int n)
{
    __shared__ int wsum[4];
    int t    = threadIdx.x;
    int lane = t & 63;
    int wid  = t >> 6;
    int idx  = blockIdx.x * 256 + t;
    int v    = (idx < n) ? deg[idx] : 0;
    int val  = v;
#pragma unroll
    for (int off = 1; off < 64; off <<= 1) {
        int y = __shfl_up(val, off);
        if (lane >= off) val += y;
    }
    if (lane == 63) wsum[wid] = val;
    __syncthreads();
    if (t == 0) {
        int s = 0;
#pragma unroll
        for (int w = 0; w < 4; ++w) { int tmp = wsum[w]; wsum[w] = s; s += tmp; }
    }
    __syncthreads();
    int excl = wsum[wid] + val - v;
    if (idx < n) offs[idx] = excl;
    if (t == 255) bsum[blockIdx.x] = wsum[3] + val;   // block total
}

__global__ __launch_bounds__(256) void scan_bsums(
    int* __restrict__ bsum, int* __restrict__ bexcl, int* __restrict__ offs, int nb, int n)
{
    __shared__ int wsum[4];
    int t    = threadIdx.x;
    int lane = t & 63;
    int wid  = t >> 6;
    int v    = (t < nb) ? bsum[t] : 0;
    int val  = v;
#pragma unroll
    for (int off = 1; off < 64; off <<= 1) {
        int y = __shfl_up(val, off);
        if (lane >= off) val += y;
    }
    if (lane == 63) wsum[wid] = val;
    __syncthreads();
    if (t == 0) {
        int s = 0;
#pragma unroll
        for (int w = 0; w < 4; ++w) { int tmp = wsum[w]; wsum[w] = s; s += tmp; }
    }
    __syncthreads();
    int excl = wsum[wid] + val - v;
    if (t < nb) bexcl[t] = excl;
    if (t == 255) offs[n] = wsum[3] + val;   // grand total = E
}

__global__ __launch_bounds__(256) void scan_apply(
    int* __restrict__ offs, int* __restrict__ cursor, const int* __restrict__ bexcl, int n)
{
    int idx = blockIdx.x * 256 + threadIdx.x;
    if (idx < n) {
        int o = offs[idx] + bexcl[blockIdx.x];
        offs[idx]   = o;
        cursor[idx] = o;
    }
}

// ---------------------------------------------------------------------------
// CSR fill: pos = cursor[dst]++ ; csr[pos] = src.
// ---------------------------------------------------------------------------
__global__ void scatter_edges(const int* __restrict__ src,
                              const int* __restrict__ dst,
                              int* __restrict__ cursor, int* __restrict__ csr, int E)
{
    int e = blockIdx.x * blockDim.x + threadIdx.x;
    if (e < E) {
        int d   = dst[e];
        int pos = atomicAdd(&cursor[d], 1);
        csr[pos] = src[e];
    }
}

// ---------------------------------------------------------------------------
// Per-node gather + mean + self + relu. One wave per node, float2 per lane.
// out already holds self part (h@Ws^T+b); update in place.
// ---------------------------------------------------------------------------
__global__ __launch_bounds__(256) void gather_finish(
    const int* __restrict__ offs,
    const int* __restrict__ csr,
    const float* __restrict__ msg,
    float* __restrict__ out,
    int n)
{
    int node = blockIdx.x * 4 + (threadIdx.x >> 6);
    if (node >= n) return;
    int lane  = threadIdx.x & 63;
    int start = offs[node];
    int end   = offs[node + 1];

    const float2* m2 = (const float2*)msg;
    float ax = 0.f, ay = 0.f;
    int i = start;
    for (; i + 4 <= end; i += 4) {
        int s0 = csr[i + 0], s1 = csr[i + 1], s2 = csr[i + 2], s3 = csr[i + 3];
        float2 v0 = m2[(size_t)s0 * 64 + lane];
        float2 v1 = m2[(size_t)s1 * 64 + lane];
        float2 v2 = m2[(size_t)s2 * 64 + lane];
        float2 v3 = m2[(size_t)s3 * 64 + lane];
        ax += v0.x + v1.x + v2.x + v3.x;
        ay += v0.y + v1.y + v2.y + v3.y;
    }
    for (; i < end; ++i) {
        int s = csr[i];
        float2 v = m2[(size_t)s * 64 + lane];
        ax += v.x; ay += v.y;
    }

    int   d  = end - start;
    float sc = d > 0 ? 1.0f / (float)d : 0.f;

    float2* o2 = (float2*)out;
    float2 sv  = o2[(size_t)node * 64 + lane];
    float2 r;
    r.x = fmaxf(sv.x + ax * sc, 0.f);
    r.y = fmaxf(sv.y + ay * sc, 0.f);
    o2[(size_t)node * 64 + lane] = r;
}

// ---------------------------------------------------------------------------
extern "C" void kernel_launch(void* const* d_in, const int* in_sizes, int n_in,
                              void* d_out, int out_size, void* d_ws, size_t ws_size,
                              hipStream_t stream)
{
    const float* h   = (const float*)d_in[0];
    const int*   src = (const int*)d_in[1];   // harness passes integer inputs as int32
    const int*   dst = (const int*)d_in[2];
    const float* We  = (const float*)d_in[3];
    const float* Ws  = (const float*)d_in[4];
    const float* bs  = (const float*)d_in[5];
    float*       out = (float*)d_out;

    const int n = in_sizes[0] / N_HID;   // 50000
    const int E = in_sizes[1];           // 800000

    // workspace layout (~29.5 MB)
    float* msg    = (float*)d_ws;                       // n*128 f32
    int*   deg    = (int*)(msg + (size_t)n * N_HID);    // n
    int*   offs   = deg + n;                            // n+1 (+pad)
    int*   cursor = offs + (n + 8);                     // n
    int*   csr    = cursor + n;                         // E
    int*   bsum   = csr + E;                            // 256
    int*   bexcl  = bsum + 256;                         // 256

    const int nbScan = (n + 255) / 256;                 // 196

    hipMemsetAsync(deg, 0, sizeof(int) * (size_t)n, stream);
    count_deg<<<(E + 255) / 256, 256, 0, stream>>>(dst, deg, E);
    scan_block<<<nbScan, 256, 0, stream>>>(deg, offs, bsum, n);
    scan_bsums<<<1, 256, 0, stream>>>(bsum, bexcl, offs, nbScan, n);
    scan_apply<<<nbScan, 256, 0, stream>>>(offs, cursor, bexcl, n);
    scatter_edges<<<(E + 255) / 256, 256, 0, stream>>>(src, dst, cursor, csr, E);
    gemm_dual<<<(n + BM - 1) / BM, 256, 0, stream>>>(h, We, Ws, bs, msg, out, n);
    gather_finish<<<(n + 3) / 4, 256, 0, stream>>>(offs, csr, msg, out, n);
}

// Round 5
// 239.577 us; speedup vs baseline: 3.4764x; 1.5758x over previous
//
#include <hip/hip_runtime.h>

#define N_HID 128

typedef short bf16x8 __attribute__((ext_vector_type(8)));
typedef float f32x4  __attribute__((ext_vector_type(4)));

// round-to-nearest-even f32 -> bf16 bits
static __device__ __forceinline__ unsigned short f2bf(float f)
{
    unsigned int u = __float_as_uint(f);
    u = (u + 0x7fffu + ((u >> 16) & 1u)) >> 16;
    return (unsigned short)u;
}
static __device__ __forceinline__ float bf2f(unsigned int bits16)
{
    return __uint_as_float(bits16 << 16);
}

// ---------------------------------------------------------------------------
// Fragmentize: f32 [rows,128] -> bf16 MFMA-fragment order.
// Frag layout per 16-row tile rt: [kc 0..3][lane 0..63][j 0..7] ushort,
// where lane = ((k>>3)&3)*16 + (row&15), j = k&7  (A/B operand layout of
// mfma_f32_16x16x32_bf16). One block per tile; blocks [0,nrt) do h,
// [nrt,nrt+8) do We, [nrt+8,nrt+16) do Ws.
// ---------------------------------------------------------------------------
__global__ __launch_bounds__(256) void fragmentize(
    const float* __restrict__ h,
    const float* __restrict__ We,
    const float* __restrict__ Ws,
    unsigned short* __restrict__ Ah,
    unsigned short* __restrict__ Be,
    unsigned short* __restrict__ Bs,
    int n, int nrt)
{
    int b = blockIdx.x;
    const float* src; unsigned short* dstF; int rt, nrows;
    if (b < nrt)          { src = h;  dstF = Ah; rt = b;          nrows = n;   }
    else if (b < nrt + 8) { src = We; dstF = Be; rt = b - nrt;    nrows = 128; }
    else                  { src = Ws; dstF = Bs; rt = b - nrt - 8; nrows = 128; }

    int t  = threadIdx.x;
    int kc = t >> 6;          // 0..3 (k-chunk of 32)
    int l  = t & 63;          // lane slot
    int m  = l & 15;          // row within tile
    int q  = l >> 4;          // k-subchunk of 8

    int row = rt * 16 + m;
    if (row > nrows - 1) row = nrows - 1;

    const float* p = &src[(size_t)row * N_HID + kc * 32 + q * 8];
    float4 v0 = *(const float4*)p;
    float4 v1 = *(const float4*)(p + 4);

    uint4 pk;
    pk.x = (unsigned int)f2bf(v0.x) | ((unsigned int)f2bf(v0.y) << 16);
    pk.y = (unsigned int)f2bf(v0.z) | ((unsigned int)f2bf(v0.w) << 16);
    pk.z = (unsigned int)f2bf(v1.x) | ((unsigned int)f2bf(v1.y) << 16);
    pk.w = (unsigned int)f2bf(v1.z) | ((unsigned int)f2bf(v1.w) << 16);

    *(uint4*)&dstF[(size_t)rt * 2048 + kc * 512 + l * 8] = pk;
}

// ---------------------------------------------------------------------------
// MFMA GEMM: one wave per 16-row tile, full 128 cols (8 col-tiles x 4 k-frags).
// A,B frags pre-laid-out: every load is lane-linear dwordx4 (coalesced).
// bias==null  -> write bf16 msg.  bias!=null -> write f32 out + bias.
// D layout: col = lane&15, row = (lane>>4)*4 + reg  (m89/m91 verified).
// ---------------------------------------------------------------------------
__global__ __launch_bounds__(256) void gemm_mfma(
    const unsigned short* __restrict__ Afrag,
    const unsigned short* __restrict__ Bfrag,
    const float* __restrict__ bias,
    unsigned short* __restrict__ msgOut,
    float* __restrict__ fOut,
    int n, int nrt)
{
    int w = (int)((blockIdx.x * blockDim.x + threadIdx.x) >> 6);
    if (w >= nrt) return;
    int l = threadIdx.x & 63;

    const bf16x8* Ap = (const bf16x8*)(Afrag + (size_t)w * 2048);
    bf16x8 a0 = Ap[l], a1 = Ap[64 + l], a2 = Ap[128 + l], a3 = Ap[192 + l];

    const int m0   = w * 16;
    const int colb = l & 15;
    const int rq   = (l >> 4) * 4;

#pragma unroll
    for (int ct = 0; ct < 8; ++ct) {
        const bf16x8* Bp = (const bf16x8*)(Bfrag + (size_t)ct * 2048);
        f32x4 acc = {0.f, 0.f, 0.f, 0.f};
        acc = __builtin_amdgcn_mfma_f32_16x16x32_bf16(a0, Bp[l],       acc, 0, 0, 0);
        acc = __builtin_amdgcn_mfma_f32_16x16x32_bf16(a1, Bp[64 + l],  acc, 0, 0, 0);
        acc = __builtin_amdgcn_mfma_f32_16x16x32_bf16(a2, Bp[128 + l], acc, 0, 0, 0);
        acc = __builtin_amdgcn_mfma_f32_16x16x32_bf16(a3, Bp[192 + l], acc, 0, 0, 0);

        int col = ct * 16 + colb;
        if (bias) {
            float bv = bias[col];
#pragma unroll
            for (int r = 0; r < 4; ++r) {
                int row = m0 + rq + r;
                if (row < n) fOut[(size_t)row * N_HID + col] = acc[r] + bv;
            }
        } else {
#pragma unroll
            for (int r = 0; r < 4; ++r) {
                int row = m0 + rq + r;
                if (row < n) msgOut[(size_t)row * N_HID + col] = f2bf(acc[r]);
            }
        }
    }
}

// ---------------------------------------------------------------------------
// Degree count: 800k int atomics over 50k counters (L2-resident).
// ---------------------------------------------------------------------------
__global__ void count_deg(const int* __restrict__ dst, int* __restrict__ deg, int E)
{
    int e = blockIdx.x * blockDim.x + threadIdx.x;
    if (e < E) atomicAdd(&deg[dst[e]], 1);
}

// ---------------------------------------------------------------------------
// Multi-block exclusive scan, 3 phases.
// ---------------------------------------------------------------------------
__global__ __launch_bounds__(256) void scan_block(
    const int* __restrict__ deg, int* __restrict__ offs, int* __restrict__ bsum, int n)
{
    __shared__ int wsum[4];
    int t    = threadIdx.x;
    int lane = t & 63;
    int wid  = t >> 6;
    int idx  = blockIdx.x * 256 + t;
    int v    = (idx < n) ? deg[idx] : 0;
    int val  = v;
#pragma unroll
    for (int off = 1; off < 64; off <<= 1) {
        int y = __shfl_up(val, off);
        if (lane >= off) val += y;
    }
    if (lane == 63) wsum[wid] = val;
    __syncthreads();
    if (t == 0) {
        int s = 0;
#pragma unroll
        for (int w = 0; w < 4; ++w) { int tmp = wsum[w]; wsum[w] = s; s += tmp; }
    }
    __syncthreads();
    int excl = wsum[wid] + val - v;
    if (idx < n) offs[idx] = excl;
    if (t == 255) bsum[blockIdx.x] = wsum[3] + val;
}

__global__ __launch_bounds__(256) void scan_bsums(
    int* __restrict__ bsum, int* __restrict__ bexcl, int* __restrict__ offs, int nb, int n)
{
    __shared__ int wsum[4];
    int t    = threadIdx.x;
    int lane = t & 63;
    int wid  = t >> 6;
    int v    = (t < nb) ? bsum[t] : 0;
    int val  = v;
#pragma unroll
    for (int off = 1; off < 64; off <<= 1) {
        int y = __shfl_up(val, off);
        if (lane >= off) val += y;
    }
    if (lane == 63) wsum[wid] = val;
    __syncthreads();
    if (t == 0) {
        int s = 0;
#pragma unroll
        for (int w = 0; w < 4; ++w) { int tmp = wsum[w]; wsum[w] = s; s += tmp; }
    }
    __syncthreads();
    int excl = wsum[wid] + val - v;
    if (t < nb) bexcl[t] = excl;
    if (t == 255) offs[n] = wsum[3] + val;   // grand total = E
}

__global__ __launch_bounds__(256) void scan_apply(
    int* __restrict__ offs, int* __restrict__ cursor, const int* __restrict__ bexcl, int n)
{
    int idx = blockIdx.x * 256 + threadIdx.x;
    if (idx < n) {
        int o = offs[idx] + bexcl[blockIdx.x];
        offs[idx]   = o;
        cursor[idx] = o;
    }
}

// ---------------------------------------------------------------------------
// CSR fill: pos = cursor[dst]++ ; csr[pos] = src.
// ---------------------------------------------------------------------------
__global__ void scatter_edges(const int* __restrict__ src,
                              const int* __restrict__ dst,
                              int* __restrict__ cursor, int* __restrict__ csr, int E)
{
    int e = blockIdx.x * blockDim.x + threadIdx.x;
    if (e < E) {
        int d   = dst[e];
        int pos = atomicAdd(&cursor[d], 1);
        csr[pos] = src[e];
    }
}

// ---------------------------------------------------------------------------
// Per-node gather(bf16 msg) + mean + self(f32, already in out) + relu.
// One wave per node; lane reads one uint = 2 bf16 (256B/row coalesced).
// ---------------------------------------------------------------------------
__global__ __launch_bounds__(256) void gather_finish(
    const int* __restrict__ offs,
    const int* __restrict__ csr,
    const unsigned short* __restrict__ msg,
    float* __restrict__ out,
    int n)
{
    int node = blockIdx.x * 4 + (threadIdx.x >> 6);
    if (node >= n) return;
    int lane  = threadIdx.x & 63;
    int start = offs[node];
    int end   = offs[node + 1];

    const unsigned int* m32 = (const unsigned int*)msg;   // 64 uints per row
    float ax = 0.f, ay = 0.f;
    int i = start;
    for (; i + 4 <= end; i += 4) {
        int s0 = csr[i + 0], s1 = csr[i + 1], s2 = csr[i + 2], s3 = csr[i + 3];
        unsigned int v0 = m32[(size_t)s0 * 64 + lane];
        unsigned int v1 = m32[(size_t)s1 * 64 + lane];
        unsigned int v2 = m32[(size_t)s2 * 64 + lane];
        unsigned int v3 = m32[(size_t)s3 * 64 + lane];
        ax += bf2f(v0 & 0xffffu) + bf2f(v1 & 0xffffu) + bf2f(v2 & 0xffffu) + bf2f(v3 & 0xffffu);
        ay += bf2f(v0 >> 16)     + bf2f(v1 >> 16)     + bf2f(v2 >> 16)     + bf2f(v3 >> 16);
    }
    for (; i < end; ++i) {
        unsigned int v = m32[(size_t)csr[i] * 64 + lane];
        ax += bf2f(v & 0xffffu);
        ay += bf2f(v >> 16);
    }

    int   d  = end - start;
    float sc = d > 0 ? 1.0f / (float)d : 0.f;

    float2* o2 = (float2*)out;
    float2 sv  = o2[(size_t)node * 64 + lane];
    float2 r;
    r.x = fmaxf(sv.x + ax * sc, 0.f);
    r.y = fmaxf(sv.y + ay * sc, 0.f);
    o2[(size_t)node * 64 + lane] = r;
}

// ---------------------------------------------------------------------------
extern "C" void kernel_launch(void* const* d_in, const int* in_sizes, int n_in,
                              void* d_out, int out_size, void* d_ws, size_t ws_size,
                              hipStream_t stream)
{
    const float* h   = (const float*)d_in[0];
    const int*   src = (const int*)d_in[1];   // harness passes integer inputs as int32
    const int*   dst = (const int*)d_in[2];
    const float* We  = (const float*)d_in[3];
    const float* Ws  = (const float*)d_in[4];
    const float* bs  = (const float*)d_in[5];
    float*       out = (float*)d_out;

    const int n   = in_sizes[0] / N_HID;    // 50000
    const int E   = in_sizes[1];            // 800000
    const int nrt = (n + 15) / 16;          // 3125 row tiles

    // workspace layout (~29.5 MB)
    unsigned short* msg   = (unsigned short*)d_ws;            // n*128 bf16
    unsigned short* Ah    = msg + (size_t)n * N_HID;          // nrt*2048 ushort
    unsigned short* Be    = Ah + (size_t)nrt * 2048;          // 8*2048
    unsigned short* Bs    = Be + 8 * 2048;                    // 8*2048
    int*   deg    = (int*)(Bs + 8 * 2048);                    // n
    int*   offs   = deg + n;                                  // n+1 (+pad)
    int*   cursor = offs + (n + 8);                           // n
    int*   csr    = cursor + n;                               // E
    int*   bsum   = csr + E;                                  // 256
    int*   bexcl  = bsum + 256;                               // 256

    const int nbScan = (n + 255) / 256;

    hipMemsetAsync(deg, 0, sizeof(int) * (size_t)n, stream);
    count_deg<<<(E + 255) / 256, 256, 0, stream>>>(dst, deg, E);
    scan_block<<<nbScan, 256, 0, stream>>>(deg, offs, bsum, n);
    scan_bsums<<<1, 256, 0, stream>>>(bsum, bexcl, offs, nbScan, n);
    scan_apply<<<nbScan, 256, 0, stream>>>(offs, cursor, bexcl, n);
    scatter_edges<<<(E + 255) / 256, 256, 0, stream>>>(src, dst, cursor, csr, E);

    fragmentize<<<nrt + 16, 256, 0, stream>>>(h, We, Ws, Ah, Be, Bs, n, nrt);
    gemm_mfma<<<(nrt + 3) / 4, 256, 0, stream>>>(Ah, Be, nullptr, msg, nullptr, n, nrt);
    gemm_mfma<<<(nrt + 3) / 4, 256, 0, stream>>>(Ah, Bs, bs, nullptr, out, n, nrt);

    gather_finish<<<(n + 3) / 4, 256, 0, stream>>>(offs, csr, msg, out, n);
}

// Round 6
// 196.456 us; speedup vs baseline: 4.2394x; 1.2195x over previous
//
#include <hip/hip_runtime.h>

#define N_HID 128
#define CAP   64          // bucket slots per node (Poisson(16) degree; overflow handled exactly)
#define OVF_CAP 8192

typedef short bf16x8 __attribute__((ext_vector_type(8)));
typedef float f32x4  __attribute__((ext_vector_type(4)));

// round-to-nearest-even f32 -> bf16 bits
static __device__ __forceinline__ unsigned short f2bf(float f)
{
    unsigned int u = __float_as_uint(f);
    u = (u + 0x7fffu + ((u >> 16) & 1u)) >> 16;
    return (unsigned short)u;
}
static __device__ __forceinline__ float bf2f(unsigned int bits16)
{
    return __uint_as_float(bits16 << 16);
}

// ---------------------------------------------------------------------------
// Fragmentize: f32 [rows,128] -> bf16 MFMA-fragment order.
// Frag layout per 16-row tile rt: [kc 0..3][lane 0..63][j 0..7] ushort,
// lane = ((k>>3)&3)*16 + (row&15), j = k&7 (A/B operand of mfma 16x16x32_bf16)
// ---------------------------------------------------------------------------
__global__ __launch_bounds__(256) void fragmentize(
    const float* __restrict__ h,
    const float* __restrict__ We,
    const float* __restrict__ Ws,
    unsigned short* __restrict__ Ah,
    unsigned short* __restrict__ Be,
    unsigned short* __restrict__ Bs,
    int n, int nrt)
{
    int b = blockIdx.x;
    const float* src; unsigned short* dstF; int rt, nrows;
    if (b < nrt)          { src = h;  dstF = Ah; rt = b;           nrows = n;   }
    else if (b < nrt + 8) { src = We; dstF = Be; rt = b - nrt;     nrows = 128; }
    else                  { src = Ws; dstF = Bs; rt = b - nrt - 8; nrows = 128; }

    int t  = threadIdx.x;
    int kc = t >> 6;          // 0..3 (k-chunk of 32)
    int l  = t & 63;          // lane slot
    int m  = l & 15;          // row within tile
    int q  = l >> 4;          // k-subchunk of 8

    int row = rt * 16 + m;
    if (row > nrows - 1) row = nrows - 1;

    const float* p = &src[(size_t)row * N_HID + kc * 32 + q * 8];
    float4 v0 = *(const float4*)p;
    float4 v1 = *(const float4*)(p + 4);

    uint4 pk;
    pk.x = (unsigned int)f2bf(v0.x) | ((unsigned int)f2bf(v0.y) << 16);
    pk.y = (unsigned int)f2bf(v0.z) | ((unsigned int)f2bf(v0.w) << 16);
    pk.z = (unsigned int)f2bf(v1.x) | ((unsigned int)f2bf(v1.y) << 16);
    pk.w = (unsigned int)f2bf(v1.z) | ((unsigned int)f2bf(v1.w) << 16);

    *(uint4*)&dstF[(size_t)rt * 2048 + kc * 512 + l * 8] = pk;
}

// ---------------------------------------------------------------------------
// MFMA GEMM: one wave per 16-row tile, 8 col-tiles x 4 k-frags.
// bias==null -> write bf16 msg. bias!=null -> write f32 out + bias.
// D layout: col = lane&15, row = (lane>>4)*4 + reg.
// ---------------------------------------------------------------------------
__global__ __launch_bounds__(256) void gemm_mfma(
    const unsigned short* __restrict__ Afrag,
    const unsigned short* __restrict__ Bfrag,
    const float* __restrict__ bias,
    unsigned short* __restrict__ msgOut,
    float* __restrict__ fOut,
    int n, int nrt)
{
    int w = (int)((blockIdx.x * blockDim.x + threadIdx.x) >> 6);
    if (w >= nrt) return;
    int l = threadIdx.x & 63;

    const bf16x8* Ap = (const bf16x8*)(Afrag + (size_t)w * 2048);
    bf16x8 a0 = Ap[l], a1 = Ap[64 + l], a2 = Ap[128 + l], a3 = Ap[192 + l];

    const int m0   = w * 16;
    const int colb = l & 15;
    const int rq   = (l >> 4) * 4;

#pragma unroll
    for (int ct = 0; ct < 8; ++ct) {
        const bf16x8* Bp = (const bf16x8*)(Bfrag + (size_t)ct * 2048);
        f32x4 acc = {0.f, 0.f, 0.f, 0.f};
        acc = __builtin_amdgcn_mfma_f32_16x16x32_bf16(a0, Bp[l],       acc, 0, 0, 0);
        acc = __builtin_amdgcn_mfma_f32_16x16x32_bf16(a1, Bp[64 + l],  acc, 0, 0, 0);
        acc = __builtin_amdgcn_mfma_f32_16x16x32_bf16(a2, Bp[128 + l], acc, 0, 0, 0);
        acc = __builtin_amdgcn_mfma_f32_16x16x32_bf16(a3, Bp[192 + l], acc, 0, 0, 0);

        int col = ct * 16 + colb;
        if (bias) {
            float bv = bias[col];
#pragma unroll
            for (int r = 0; r < 4; ++r) {
                int row = m0 + rq + r;
                if (row < n) fOut[(size_t)row * N_HID + col] = acc[r] + bv;
            }
        } else {
#pragma unroll
            for (int r = 0; r < 4; ++r) {
                int row = m0 + rq + r;
                if (row < n) msgOut[(size_t)row * N_HID + col] = f2bf(acc[r]);
            }
        }
    }
}

// ---------------------------------------------------------------------------
// One-pass bucket scatter: c = cnt[d]++ ; bucket[d*CAP+c] = src (c<CAP).
// Overflow (never on this data, exact if it happens): packed (d,src) list.
// ---------------------------------------------------------------------------
__global__ void bucket_scatter(const int* __restrict__ src,
                               const int* __restrict__ dst,
                               int* __restrict__ cnt,
                               int* __restrict__ bucket,
                               int* __restrict__ ovfn,
                               long long* __restrict__ ovf,
                               int E)
{
    int e = blockIdx.x * blockDim.x + threadIdx.x;
    if (e < E) {
        int d = dst[e];
        int s = src[e];
        int c = atomicAdd(&cnt[d], 1);
        if (c < CAP) {
            bucket[(size_t)d * CAP + c] = s;
        } else {
            int o = atomicAdd(ovfn, 1);
            if (o < OVF_CAP) ovf[o] = ((long long)d << 32) | (unsigned int)s;
        }
    }
}

// ---------------------------------------------------------------------------
// Per-node gather(bf16 msg) + mean + self(f32, already in out) + relu.
// One wave per node; lane reads one uint = 2 bf16 (256B/row coalesced).
// ---------------------------------------------------------------------------
__global__ __launch_bounds__(256) void gather_finish(
    const int* __restrict__ cnt,
    const int* __restrict__ bucket,
    const int* __restrict__ ovfn,
    const long long* __restrict__ ovf,
    const unsigned short* __restrict__ msg,
    float* __restrict__ out,
    int n)
{
    int node = blockIdx.x * 4 + (threadIdx.x >> 6);
    if (node >= n) return;
    int lane = threadIdx.x & 63;
    int deg  = cnt[node];
    int m    = deg < CAP ? deg : CAP;

    const int* bk = &bucket[(size_t)node * CAP];
    const unsigned int* m32 = (const unsigned int*)msg;   // 64 uints per row

    float ax = 0.f, ay = 0.f;
    int i = 0;
    for (; i + 4 <= m; i += 4) {
        int s0 = bk[i + 0], s1 = bk[i + 1], s2 = bk[i + 2], s3 = bk[i + 3];
        unsigned int v0 = m32[(size_t)s0 * 64 + lane];
        unsigned int v1 = m32[(size_t)s1 * 64 + lane];
        unsigned int v2 = m32[(size_t)s2 * 64 + lane];
        unsigned int v3 = m32[(size_t)s3 * 64 + lane];
        ax += bf2f(v0 & 0xffffu) + bf2f(v1 & 0xffffu) + bf2f(v2 & 0xffffu) + bf2f(v3 & 0xffffu);
        ay += bf2f(v0 >> 16)     + bf2f(v1 >> 16)     + bf2f(v2 >> 16)     + bf2f(v3 >> 16);
    }
    for (; i < m; ++i) {
        unsigned int v = m32[(size_t)bk[i] * 64 + lane];
        ax += bf2f(v & 0xffffu);
        ay += bf2f(v >> 16);
    }

    if (deg > CAP) {                 // exact fallback; never taken on this data
        int no = *ovfn; if (no > OVF_CAP) no = OVF_CAP;
        for (int o = 0; o < no; ++o) {
            long long pk = ovf[o];
            if ((int)(pk >> 32) == node) {
                unsigned int v = m32[(size_t)(unsigned int)pk * 64 + lane];
                ax += bf2f(v & 0xffffu);
                ay += bf2f(v >> 16);
            }
        }
    }

    float sc = deg > 0 ? 1.0f / (float)deg : 0.f;

    float2* o2 = (float2*)out;
    float2 sv  = o2[(size_t)node * 64 + lane];
    float2 r;
    r.x = fmaxf(sv.x + ax * sc, 0.f);
    r.y = fmaxf(sv.y + ay * sc, 0.f);
    o2[(size_t)node * 64 + lane] = r;
}

// ---------------------------------------------------------------------------
extern "C" void kernel_launch(void* const* d_in, const int* in_sizes, int n_in,
                              void* d_out, int out_size, void* d_ws, size_t ws_size,
                              hipStream_t stream)
{
    const float* h   = (const float*)d_in[0];
    const int*   src = (const int*)d_in[1];
    const int*   dst = (const int*)d_in[2];
    const float* We  = (const float*)d_in[3];
    const float* Ws  = (const float*)d_in[4];
    const float* bs  = (const float*)d_in[5];
    float*       out = (float*)d_out;

    const int n   = in_sizes[0] / N_HID;    // 50000
    const int E   = in_sizes[1];            // 800000
    const int nrt = (n + 15) / 16;          // 3125 row tiles

    // workspace (~26 MB). NOTE: bucket ALIASES Ah — legal because the stream
    // order is fragmentize -> gemm x2 (last readers of Ah) -> bucket_scatter
    // (writer of bucket) -> gather.
    unsigned short* msg = (unsigned short*)d_ws;              // n*128 bf16      (12.8 MB)
    unsigned short* Ah  = msg + (size_t)n * N_HID;            // nrt*2048 ushort (12.8 MB)
    int*            bucket = (int*)Ah;                        // n*CAP int       (same 12.8 MB)
    unsigned short* Be  = Ah + (size_t)nrt * 2048;            // 8*2048
    unsigned short* Bs  = Be + 8 * 2048;                      // 8*2048
    int*  cnt  = (int*)(Bs + 8 * 2048);                       // n
    int*  ovfn = cnt + n;                                     // 1
    long long* ovf = (long long*)(ovfn + 8);                  // OVF_CAP

    hipMemsetAsync(cnt, 0, sizeof(int) * (size_t)(n + 8), stream);
    fragmentize<<<nrt + 16, 256, 0, stream>>>(h, We, Ws, Ah, Be, Bs, n, nrt);
    gemm_mfma<<<(nrt + 3) / 4, 256, 0, stream>>>(Ah, Be, nullptr, msg, nullptr, n, nrt);
    gemm_mfma<<<(nrt + 3) / 4, 256, 0, stream>>>(Ah, Bs, bs, nullptr, out, n, nrt);
    bucket_scatter<<<(E + 255) / 256, 256, 0, stream>>>(src, dst, cnt, bucket, ovfn, ovf, E);
    gather_finish<<<(n + 3) / 4, 256, 0, stream>>>(cnt, bucket, ovfn, ovf, msg, out, n);
}

// Round 7
// 189.173 us; speedup vs baseline: 4.4026x; 1.0385x over previous
//
#include <hip/hip_runtime.h>

#define N_HID 128
#define CAP   64          // bucket slots per node (Poisson(16) degree; overflow handled exactly)
#define OVF_CAP 8192

typedef short bf16x8 __attribute__((ext_vector_type(8)));
typedef float f32x4  __attribute__((ext_vector_type(4)));

// round-to-nearest-even f32 -> bf16 bits
static __device__ __forceinline__ unsigned short f2bf(float f)
{
    unsigned int u = __float_as_uint(f);
    u = (u + 0x7fffu + ((u >> 16) & 1u)) >> 16;
    return (unsigned short)u;
}
static __device__ __forceinline__ float bf2f(unsigned int bits16)
{
    return __uint_as_float(bits16 << 16);
}

// ---------------------------------------------------------------------------
// Fragmentize: f32 [rows,128] -> bf16 MFMA-fragment order.
// Frag layout per 16-row tile rt: [kc 0..3][lane 0..63][j 0..7] ushort,
// lane = ((k>>3)&3)*16 + (row&15), j = k&7 (A/B operand of mfma 16x16x32_bf16)
// ---------------------------------------------------------------------------
__global__ __launch_bounds__(256) void fragmentize(
    const float* __restrict__ h,
    const float* __restrict__ We,
    const float* __restrict__ Ws,
    unsigned short* __restrict__ Ah,
    unsigned short* __restrict__ Be,
    unsigned short* __restrict__ Bs,
    int n, int nrt)
{
    int b = blockIdx.x;
    const float* src; unsigned short* dstF; int rt, nrows;
    if (b < nrt)          { src = h;  dstF = Ah; rt = b;           nrows = n;   }
    else if (b < nrt + 8) { src = We; dstF = Be; rt = b - nrt;     nrows = 128; }
    else                  { src = Ws; dstF = Bs; rt = b - nrt - 8; nrows = 128; }

    int t  = threadIdx.x;
    int kc = t >> 6;          // 0..3 (k-chunk of 32)
    int l  = t & 63;          // lane slot
    int m  = l & 15;          // row within tile
    int q  = l >> 4;          // k-subchunk of 8

    int row = rt * 16 + m;
    if (row > nrows - 1) row = nrows - 1;

    const float* p = &src[(size_t)row * N_HID + kc * 32 + q * 8];
    float4 v0 = *(const float4*)p;
    float4 v1 = *(const float4*)(p + 4);

    uint4 pk;
    pk.x = (unsigned int)f2bf(v0.x) | ((unsigned int)f2bf(v0.y) << 16);
    pk.y = (unsigned int)f2bf(v0.z) | ((unsigned int)f2bf(v0.w) << 16);
    pk.z = (unsigned int)f2bf(v1.x) | ((unsigned int)f2bf(v1.y) << 16);
    pk.w = (unsigned int)f2bf(v1.z) | ((unsigned int)f2bf(v1.w) << 16);

    *(uint4*)&dstF[(size_t)rt * 2048 + kc * 512 + l * 8] = pk;
}

// ---------------------------------------------------------------------------
// Fused dual MFMA GEMM in ONE launch: blocks [0,nwb) do We->msg(bf16),
// blocks [nwb,2*nwb) do Ws->out(f32)+bias. One wave per 16-row tile.
// D layout: col = lane&15, row = (lane>>4)*4 + reg.
// ---------------------------------------------------------------------------
__global__ __launch_bounds__(256) void gemm_mfma2(
    const unsigned short* __restrict__ Afrag,
    const unsigned short* __restrict__ Be,
    const unsigned short* __restrict__ Bsf,
    const float* __restrict__ bias,
    unsigned short* __restrict__ msgOut,
    float* __restrict__ fOut,
    int n, int nrt, int nwb)
{
    int b    = blockIdx.x;
    bool sp  = b >= nwb;             // self pass?
    int bl   = sp ? b - nwb : b;
    int w    = bl * 4 + ((int)threadIdx.x >> 6);
    if (w >= nrt) return;
    int l = threadIdx.x & 63;

    const unsigned short* Bfrag = sp ? Bsf : Be;

    const bf16x8* Ap = (const bf16x8*)(Afrag + (size_t)w * 2048);
    bf16x8 a0 = Ap[l], a1 = Ap[64 + l], a2 = Ap[128 + l], a3 = Ap[192 + l];

    const int m0   = w * 16;
    const int colb = l & 15;
    const int rq   = (l >> 4) * 4;

#pragma unroll
    for (int ct = 0; ct < 8; ++ct) {
        const bf16x8* Bp = (const bf16x8*)(Bfrag + (size_t)ct * 2048);
        f32x4 acc = {0.f, 0.f, 0.f, 0.f};
        acc = __builtin_amdgcn_mfma_f32_16x16x32_bf16(a0, Bp[l],       acc, 0, 0, 0);
        acc = __builtin_amdgcn_mfma_f32_16x16x32_bf16(a1, Bp[64 + l],  acc, 0, 0, 0);
        acc = __builtin_amdgcn_mfma_f32_16x16x32_bf16(a2, Bp[128 + l], acc, 0, 0, 0);
        acc = __builtin_amdgcn_mfma_f32_16x16x32_bf16(a3, Bp[192 + l], acc, 0, 0, 0);

        int col = ct * 16 + colb;
        if (sp) {
            float bv = bias[col];
#pragma unroll
            for (int r = 0; r < 4; ++r) {
                int row = m0 + rq + r;
                if (row < n) fOut[(size_t)row * N_HID + col] = acc[r] + bv;
            }
        } else {
#pragma unroll
            for (int r = 0; r < 4; ++r) {
                int row = m0 + rq + r;
                if (row < n) msgOut[(size_t)row * N_HID + col] = f2bf(acc[r]);
            }
        }
    }
}

// ---------------------------------------------------------------------------
// XCD-sliced bucket scatter. slice = blockIdx&7 (~XCD under round-robin
// dispatch); slice-group scans ALL edges, processes only dst in its node
// range -> each node's bucket/cnt lines are written from ONE XCD and stay
// L2-resident until full. Correctness does NOT depend on the mapping: every
// edge is processed by exactly one block by construction.
// ---------------------------------------------------------------------------
__global__ __launch_bounds__(256) void bucket_scatter(
    const int* __restrict__ src,
    const int* __restrict__ dst,
    int* __restrict__ cnt,
    int* __restrict__ bucket,
    int* __restrict__ ovfn,
    long long* __restrict__ ovf,
    int E, int n)
{
    const int slice = blockIdx.x & 7;
    const int g     = blockIdx.x >> 3;
    const int nG    = (int)(gridDim.x >> 3);
    const int lo    = (int)(((long long)slice * n) / 8);
    const int hi    = (int)(((long long)(slice + 1) * n) / 8);

    const int chunk = (E + nG - 1) / nG;
    const int e0 = g * chunk;
    const int e1 = (e0 + chunk < E) ? e0 + chunk : E;

    for (int e = e0 + (int)threadIdx.x; e < e1; e += 256) {
        int d = dst[e];
        if (d >= lo && d < hi) {
            int s = src[e];
            int c = atomicAdd(&cnt[d], 1);
            if (c < CAP) {
                bucket[(size_t)d * CAP + c] = s;
            } else {
                int o = atomicAdd(ovfn, 1);
                if (o < OVF_CAP) ovf[o] = ((long long)d << 32) | (unsigned int)s;
            }
        }
    }
}

// ---------------------------------------------------------------------------
// Per-node gather(bf16 msg) + mean + self(f32, already in out) + relu.
// One wave per node; lane reads one uint = 2 bf16 (256B/row coalesced).
// ---------------------------------------------------------------------------
__global__ __launch_bounds__(256) void gather_finish(
    const int* __restrict__ cnt,
    const int* __restrict__ bucket,
    const int* __restrict__ ovfn,
    const long long* __restrict__ ovf,
    const unsigned short* __restrict__ msg,
    float* __restrict__ out,
    int n)
{
    int node = blockIdx.x * 4 + (threadIdx.x >> 6);
    if (node >= n) return;
    int lane = threadIdx.x & 63;
    int deg  = cnt[node];
    int m    = deg < CAP ? deg : CAP;

    const int* bk = &bucket[(size_t)node * CAP];
    const unsigned int* m32 = (const unsigned int*)msg;   // 64 uints per row

    float ax = 0.f, ay = 0.f;
    int i = 0;
    for (; i + 4 <= m; i += 4) {
        int s0 = bk[i + 0], s1 = bk[i + 1], s2 = bk[i + 2], s3 = bk[i + 3];
        unsigned int v0 = m32[(size_t)s0 * 64 + lane];
        unsigned int v1 = m32[(size_t)s1 * 64 + lane];
        unsigned int v2 = m32[(size_t)s2 * 64 + lane];
        unsigned int v3 = m32[(size_t)s3 * 64 + lane];
        ax += bf2f(v0 & 0xffffu) + bf2f(v1 & 0xffffu) + bf2f(v2 & 0xffffu) + bf2f(v3 & 0xffffu);
        ay += bf2f(v0 >> 16)     + bf2f(v1 >> 16)     + bf2f(v2 >> 16)     + bf2f(v3 >> 16);
    }
    for (; i < m; ++i) {
        unsigned int v = m32[(size_t)bk[i] * 64 + lane];
        ax += bf2f(v & 0xffffu);
        ay += bf2f(v >> 16);
    }

    if (deg > CAP) {                 // exact fallback; never taken on this data
        int no = *ovfn; if (no > OVF_CAP) no = OVF_CAP;
        for (int o = 0; o < no; ++o) {
            long long pk = ovf[o];
            if ((int)(pk >> 32) == node) {
                unsigned int v = m32[(size_t)(unsigned int)pk * 64 + lane];
                ax += bf2f(v & 0xffffu);
                ay += bf2f(v >> 16);
            }
        }
    }

    float sc = deg > 0 ? 1.0f / (float)deg : 0.f;

    float2* o2 = (float2*)out;
    float2 sv  = o2[(size_t)node * 64 + lane];
    float2 r;
    r.x = fmaxf(sv.x + ax * sc, 0.f);
    r.y = fmaxf(sv.y + ay * sc, 0.f);
    o2[(size_t)node * 64 + lane] = r;
}

// ---------------------------------------------------------------------------
extern "C" void kernel_launch(void* const* d_in, const int* in_sizes, int n_in,
                              void* d_out, int out_size, void* d_ws, size_t ws_size,
                              hipStream_t stream)
{
    const float* h   = (const float*)d_in[0];
    const int*   src = (const int*)d_in[1];
    const int*   dst = (const int*)d_in[2];
    const float* We  = (const float*)d_in[3];
    const float* Ws  = (const float*)d_in[4];
    const float* bs  = (const float*)d_in[5];
    float*       out = (float*)d_out;

    const int n   = in_sizes[0] / N_HID;    // 50000
    const int E   = in_sizes[1];            // 800000
    const int nrt = (n + 15) / 16;          // 3125 row tiles
    const int nwb = (nrt + 3) / 4;          // wave-blocks per gemm pass

    // workspace (~26 MB). NOTE: bucket ALIASES Ah — legal because the stream
    // order is fragmentize -> gemm (last reader of Ah) -> bucket_scatter
    // (writer of bucket) -> gather.
    unsigned short* msg = (unsigned short*)d_ws;              // n*128 bf16      (12.8 MB)
    unsigned short* Ah  = msg + (size_t)n * N_HID;            // nrt*2048 ushort (12.8 MB)
    int*            bucket = (int*)Ah;                        // n*CAP int       (same 12.8 MB)
    unsigned short* Be  = Ah + (size_t)nrt * 2048;            // 8*2048
    unsigned short* Bs  = Be + 8 * 2048;                      // 8*2048
    int*  cnt  = (int*)(Bs + 8 * 2048);                       // n
    int*  ovfn = cnt + n;                                     // 1
    long long* ovf = (long long*)(ovfn + 8);                  // OVF_CAP

    hipMemsetAsync(cnt, 0, sizeof(int) * (size_t)(n + 8), stream);
    fragmentize<<<nrt + 16, 256, 0, stream>>>(h, We, Ws, Ah, Be, Bs, n, nrt);
    gemm_mfma2<<<2 * nwb, 256, 0, stream>>>(Ah, Be, Bs, bs, msg, out, n, nrt, nwb);
    bucket_scatter<<<512, 256, 0, stream>>>(src, dst, cnt, bucket, ovfn, ovf, E, n);
    gather_finish<<<(n + 3) / 4, 256, 0, stream>>>(cnt, bucket, ovfn, ovf, msg, out, n);
}